// Round 7
// baseline (389.081 us; speedup 1.0000x reference)
//
#include <hip/hip_runtime.h>

#define NPTS 131072

#define FRAG0_OFF    0
#define FRAG0_BYTES  4096
#define FRAGH_OFF    4096
#define HLAYER_BYTES 32768
#define FRAGH_BYTES  (3 * HLAYER_BYTES)
#define BIAS_OFF     (FRAGH_OFF + FRAGH_BYTES)   // 102400
#define BIAS_BYTES   2048
#define WO_OFF       (BIAS_OFF + BIAS_BYTES)     // 104448
#define WOBO_BYTES   528
#define MLP_BYTES    (WO_OFF + WOBO_BYTES)       // dp at 0, ic at MLP_BYTES

typedef _Float16 f16;
typedef __attribute__((ext_vector_type(8)))  _Float16 f16x8;
typedef __attribute__((ext_vector_type(16))) float    f32x16;

#define C2LOG2E 2.8853900817779268f   // 2*log2(e), folded into W/b of all layers

// tanh(true_x) where x = C2LOG2E*true_x is the folded pre-activation
__device__ __forceinline__ float tanh2(float x){
  float e = __builtin_amdgcn_exp2f(x);
  return 1.0f - 2.0f * __builtin_amdgcn_rcpf(e + 1.0f);
}

// ---------------- weight packing (r1 layout + C2LOG2E fold on W,b; Wo/bo raw) ----
__global__ void pack_weights(
    const float* __restrict__ dpW0, const float* __restrict__ dpb0,
    const float* __restrict__ dpWh, const float* __restrict__ dpbh,
    const float* __restrict__ dpWo, const float* __restrict__ dpbo,
    const float* __restrict__ icW0, const float* __restrict__ icb0,
    const float* __restrict__ icWh, const float* __restrict__ icbh,
    const float* __restrict__ icWo, const float* __restrict__ icbo,
    unsigned char* __restrict__ ws)
{
  int tid = blockIdx.x * blockDim.x + threadIdx.x;
  int nth = gridDim.x * blockDim.x;
  for (int m = 0; m < 2; ++m){
    const float* W0 = m ? icW0 : dpW0;
    const float* Wh = m ? icWh : dpWh;
    const float* b0 = m ? icb0 : dpb0;
    const float* bh = m ? icbh : dpbh;
    const float* Wo = m ? icWo : dpWo;
    const float* bo = m ? icbo : dpbo;
    const int indim = m ? 5 : 6;
    unsigned char* base = ws + m * MLP_BYTES;

    f16* dstF0 = (f16*)(base + FRAG0_OFF);
    for (int idx = tid; idx < 2048; idx += nth){
      int e    = idx & 7;
      int lane = (idx >> 3) & 63;
      int jt   = idx >> 9;
      int j = 32*jt + (lane & 31);
      int k = 8*(lane >> 5) + e;
      float v = (k < indim) ? W0[k*128 + j] * C2LOG2E : 0.0f;
      dstF0[idx] = (f16)v;
    }
    f16* dstFH = (f16*)(base + FRAGH_OFF);
    for (int idx = tid; idx < 3*16384; idx += nth){
      int layer = idx / 16384;
      int q     = idx & 16383;
      int e    = q & 7;
      int lane = (q >> 3) & 63;
      int f    = q >> 9;            // f = jt*8 + s
      int jt = f >> 3, s = f & 7;
      int j = 32*jt + (lane & 31);
      int k = 16*s + 8*(lane >> 5) + e;
      int row = (k & ~12) | ((k & 4) << 1) | ((k & 8) >> 1); // sigma: swap bits 2,3
      float v = Wh[(layer*128 + row)*128 + j] * C2LOG2E;
      dstFH[idx] = (f16)v;
    }
    float* dstB = (float*)(base + BIAS_OFF);
    for (int idx = tid; idx < 512; idx += nth)
      dstB[idx] = ((idx < 128) ? b0[idx] : bh[idx - 128]) * C2LOG2E;
    float* dstW = (float*)(base + WO_OFF);
    for (int idx = tid; idx < 128; idx += nth) dstW[idx] = Wo[idx];
    if (tid == 0) dstW[128] = bo[0];
  }
}

// ---------------- main fused kernel ----------------
__device__ __forceinline__ f32x16 load_bias16(const float* bp){
  float4 q0 = *(const float4*)(bp +  0);
  float4 q1 = *(const float4*)(bp +  8);
  float4 q2 = *(const float4*)(bp + 16);
  float4 q3 = *(const float4*)(bp + 24);
  f32x16 a;
  a[0]=q0.x;  a[1]=q0.y;  a[2]=q0.z;  a[3]=q0.w;
  a[4]=q1.x;  a[5]=q1.y;  a[6]=q1.z;  a[7]=q1.w;
  a[8]=q2.x;  a[9]=q2.y;  a[10]=q2.z; a[11]=q2.w;
  a[12]=q3.x; a[13]=q3.y; a[14]=q3.z; a[15]=q3.w;
  return a;
}

// 2048 blocks x 256 threads (4 waves). Block owns 64 points (2 column-tiles).
// Wave w holds rows [32w,32w+32) of ALL layers in VGPRs (25 A-frags = 100 regs).
// LDS (~20KB): per-layer tanh-activation exchange (swizzled), bias/Wo, partials.
__global__ __launch_bounds__(256, 8) void node_main(
    const float* __restrict__ tx,
    const unsigned char* __restrict__ ws,
    float* __restrict__ out)
{
  __shared__ __align__(16) unsigned char sH[16384];  // [ct][col 32][k 128] f16, swizzled
  __shared__ __align__(16) float sBias[512];
  __shared__ __align__(16) float sWo[136];
  __shared__ float sPart[4][2][32];

  const int tid  = threadIdx.x;
  const int wave = tid >> 6;
  const int lane = tid & 63;
  const int c    = lane & 31;
  const int hi   = lane >> 5;
  const int base = blockIdx.x * 64;
  const int swz  = (c & 15) << 4;
  const int colb = c * 256;

  // ---- features (both hi halves load the same point: broadcast) ----
  float u[2], cth[2], sth[2], cph[2], sph[2], th[2];
  #pragma unroll
  for (int ct = 0; ct < 2; ++ct){
    float4 cc = ((const float4*)tx)[base + ct*32 + c];
    float x = cc.y, y = cc.z, z = cc.w;
    float xy = x*x + y*y;
    float r    = sqrtf(xy + z*z + 1e-8f);
    float rho  = sqrtf(xy + 1e-8f);
    float rin  = __builtin_amdgcn_rcpf(r);
    float rhin = __builtin_amdgcn_rcpf(rho);
    u[ct]   = r * __builtin_amdgcn_rcpf(1.0f + r);
    cth[ct] = z * rin;
    sth[ct] = rho * rin;
    cph[ct] = x * rhin;
    sph[ct] = y * rhin;
    th[ct]  = 0.5f * cc.x;     // a = t/2 (t0 = 0)
  }

  // ---- per-wave weight slab in registers ----
  f16x8 a0;
  f16x8 fh[3][8];
  auto load_slab = [&](const unsigned char* mb){
    a0 = *(const f16x8*)(mb + FRAG0_OFF + (wave*64 + lane)*16);
    #pragma unroll
    for (int L = 0; L < 3; ++L)
      #pragma unroll
      for (int s = 0; s < 8; ++s)
        fh[L][s] = *(const f16x8*)(mb + FRAGH_OFF + L*HLAYER_BYTES
                                   + ((wave*8 + s)*64 + lane)*16);
  };
  auto stage_small = [&](const unsigned char* mb){
    for (int i = tid; i < 128; i += 256)
      ((uint4*)sBias)[i] = ((const uint4*)(mb + BIAS_OFF))[i];
    for (int i = tid; i < 33; i += 256)
      ((uint4*)sWo)[i] = ((const uint4*)(mb + WO_OFF))[i];
  };

  float vsum[2] = {0.0f, 0.0f};

  auto run_chain = [&](int chain){
    const float gn = (chain == 0) ? -0.7745966692414834f :
                     (chain == 2) ?  0.7745966692414834f : 0.0f;
    // input B-frag: k-slot = feature index (hi half = zero padding)
    f16x8 b0f[2];
    #pragma unroll
    for (int ct = 0; ct < 2; ++ct){
      #pragma unroll
      for (int e = 0; e < 8; ++e) b0f[ct][e] = (f16)0.0f;
      if (hi == 0){
        if (chain == 3){
          b0f[ct][0]=(f16)u[ct];   b0f[ct][1]=(f16)cth[ct];
          b0f[ct][2]=(f16)sth[ct]; b0f[ct][3]=(f16)cph[ct];
          b0f[ct][4]=(f16)sph[ct];
        } else {
          float ts = th[ct] * (1.0f + gn);
          b0f[ct][0]=(f16)ts;      b0f[ct][1]=(f16)u[ct];
          b0f[ct][2]=(f16)cth[ct]; b0f[ct][3]=(f16)sth[ct];
          b0f[ct][4]=(f16)cph[ct]; b0f[ct][5]=(f16)sph[ct];
        }
      }
    }

    f32x16 acc[2];
    #pragma unroll
    for (int ct = 0; ct < 2; ++ct)
      acc[ct] = __builtin_amdgcn_mfma_f32_32x32x16_f16(
                  a0, b0f[ct], load_bias16(&sBias[32*wave + 4*hi]), 0,0,0);

    #pragma unroll
    for (int L = 0; L < 3; ++L){
      // tanh + pack + swizzled exchange write (k-slot = sigma(global row))
      #pragma unroll
      for (int ct = 0; ct < 2; ++ct){
        unsigned char* tb = sH + ct*8192;
        #pragma unroll
        for (int p = 0; p < 8; ++p){
          float t0 = tanh2(acc[ct][2*p]);
          float t1 = tanh2(acc[ct][2*p + 1]);
          auto pk = __builtin_amdgcn_cvt_pkrtz(t0, t1);
          const int kb2 = 64*wave + 32*(p>>2) + 16*hi + 8*((p>>1)&1) + 4*(p&1);
          *(unsigned*)(tb + ((colb + kb2) ^ swz)) = __builtin_bit_cast(unsigned, pk);
        }
      }
      __syncthreads();                 // exchange visible
      #pragma unroll
      for (int ct = 0; ct < 2; ++ct){
        const unsigned char* tb = sH + ct*8192;
        f16x8 bfr[8];
        #pragma unroll
        for (int s = 0; s < 8; ++s)
          bfr[s] = *(const f16x8*)(tb + ((colb + 32*s + 16*hi) ^ swz));
        f32x16 t = load_bias16(&sBias[(L+1)*128 + 32*wave + 4*hi]);
        #pragma unroll
        for (int s = 0; s < 8; ++s)
          t = __builtin_amdgcn_mfma_f32_32x32x16_f16(fh[L][s], bfr[s], t, 0,0,0);
        acc[ct] = t;
      }
      __syncthreads();                 // reads done -> next layer may overwrite
    }

    // output: per-wave partial dot, reduce via sPart
    #pragma unroll
    for (int ct = 0; ct < 2; ++ct){
      const float* wp = &sWo[32*wave + 4*hi];
      float4 q0 = *(const float4*)(wp +  0);
      float4 q1 = *(const float4*)(wp +  8);
      float4 q2 = *(const float4*)(wp + 16);
      float4 q3 = *(const float4*)(wp + 24);
      f32x16 A = acc[ct];
      float v = tanh2(A[0])*q0.x  + tanh2(A[1])*q0.y
              + tanh2(A[2])*q0.z  + tanh2(A[3])*q0.w
              + tanh2(A[4])*q1.x  + tanh2(A[5])*q1.y
              + tanh2(A[6])*q1.z  + tanh2(A[7])*q1.w
              + tanh2(A[8])*q2.x  + tanh2(A[9])*q2.y
              + tanh2(A[10])*q2.z + tanh2(A[11])*q2.w
              + tanh2(A[12])*q3.x + tanh2(A[13])*q3.y
              + tanh2(A[14])*q3.z + tanh2(A[15])*q3.w;
      v += __shfl_xor(v, 32);          // combine the two row-halves
      if (hi == 0) sPart[wave][ct][c] = v;
    }
    __syncthreads();
    #pragma unroll
    for (int ct = 0; ct < 2; ++ct){
      float tot = sPart[0][ct][c] + sPart[1][ct][c]
                + sPart[2][ct][c] + sPart[3][ct][c] + sWo[128];
      if (chain == 3) vsum[ct] += tot;
      else {
        const float wq = (chain == 1) ? 0.8888888888888889f
                                      : 0.5555555555555556f;
        vsum[ct] = __builtin_fmaf(th[ct] * wq, tot, vsum[ct]);
      }
    }
  };

  load_slab(ws);                 // dp slab -> registers
  stage_small(ws);
  __syncthreads();
  #pragma unroll 1
  for (int chain = 0; chain < 3; ++chain) run_chain(chain);
  __syncthreads();               // all done with dp sBias/sWo/sPart
  load_slab(ws + MLP_BYTES);     // ic slab over the same registers
  stage_small(ws + MLP_BYTES);
  __syncthreads();
  run_chain(3);

  if (wave == 0 && hi == 0){
    out[base + c]      = vsum[0];
    out[base + 32 + c] = vsum[1];
  }
}

extern "C" void kernel_launch(void* const* d_in, const int* in_sizes, int n_in,
                              void* d_out, int out_size, void* d_ws, size_t ws_size,
                              hipStream_t stream)
{
  const float* tx = (const float*)d_in[0];
  pack_weights<<<64, 256, 0, stream>>>(
      (const float*)d_in[1],  (const float*)d_in[2],  (const float*)d_in[3],
      (const float*)d_in[4],  (const float*)d_in[5],  (const float*)d_in[6],
      (const float*)d_in[7],  (const float*)d_in[8],  (const float*)d_in[9],
      (const float*)d_in[10], (const float*)d_in[11], (const float*)d_in[12],
      (unsigned char*)d_ws);
  node_main<<<NPTS/64, 256, 0, stream>>>(tx, (const unsigned char*)d_ws, (float*)d_out);
}

// Round 8
// 129.100 us; speedup vs baseline: 3.0138x; 3.0138x over previous
//
#include <hip/hip_runtime.h>

#define NPTS 131072

#define FRAG0_OFF    0
#define FRAG0_BYTES  4096
#define FRAGH_OFF    4096
#define HLAYER_BYTES 32768
#define FRAGH_BYTES  (3 * HLAYER_BYTES)
#define WCHUNKS      100                         // (FRAG0+FRAGH)/1024
#define BIAS_OFF     (FRAGH_OFF + FRAGH_BYTES)   // 102400
#define BIAS_BYTES   2048
#define WO_OFF       (BIAS_OFF + BIAS_BYTES)     // 104448
#define WOBO_BYTES   528
#define MLP_BYTES    (WO_OFF + WOBO_BYTES)       // dp at 0, ic at MLP_BYTES

typedef _Float16 f16;
typedef __attribute__((ext_vector_type(8)))  _Float16 f16x8;
typedef __attribute__((ext_vector_type(16))) float    f32x16;

#define C2LOG2E 2.8853900817779268f   // 2*log2(e), folded into W/b of all layers

// tanh(true_x) where x = C2LOG2E*true_x is the folded pre-activation
__device__ __forceinline__ float tanh2(float x){
  float e = __builtin_amdgcn_exp2f(x);
  return 1.0f - 2.0f * __builtin_amdgcn_rcpf(e + 1.0f);
}

__device__ __forceinline__ void gl_lds16(const void* g, void* l){
  __builtin_amdgcn_global_load_lds(
      (const __attribute__((address_space(1))) void*)g,
      (__attribute__((address_space(3))) void*)l, 16, 0, 0);
}

// ---------------- weight packing (r7 layout, verified: C2LOG2E fold on W,b) ----
__global__ void pack_weights(
    const float* __restrict__ dpW0, const float* __restrict__ dpb0,
    const float* __restrict__ dpWh, const float* __restrict__ dpbh,
    const float* __restrict__ dpWo, const float* __restrict__ dpbo,
    const float* __restrict__ icW0, const float* __restrict__ icb0,
    const float* __restrict__ icWh, const float* __restrict__ icbh,
    const float* __restrict__ icWo, const float* __restrict__ icbo,
    unsigned char* __restrict__ ws)
{
  int tid = blockIdx.x * blockDim.x + threadIdx.x;
  int nth = gridDim.x * blockDim.x;
  for (int m = 0; m < 2; ++m){
    const float* W0 = m ? icW0 : dpW0;
    const float* Wh = m ? icWh : dpWh;
    const float* b0 = m ? icb0 : dpb0;
    const float* bh = m ? icbh : dpbh;
    const float* Wo = m ? icWo : dpWo;
    const float* bo = m ? icbo : dpbo;
    const int indim = m ? 5 : 6;
    unsigned char* base = ws + m * MLP_BYTES;

    f16* dstF0 = (f16*)(base + FRAG0_OFF);
    for (int idx = tid; idx < 2048; idx += nth){
      int e    = idx & 7;
      int lane = (idx >> 3) & 63;
      int jt   = idx >> 9;
      int j = 32*jt + (lane & 31);
      int k = 8*(lane >> 5) + e;
      float v = (k < indim) ? W0[k*128 + j] * C2LOG2E : 0.0f;
      dstF0[idx] = (f16)v;
    }
    f16* dstFH = (f16*)(base + FRAGH_OFF);
    for (int idx = tid; idx < 3*16384; idx += nth){
      int layer = idx / 16384;
      int q     = idx & 16383;
      int e    = q & 7;
      int lane = (q >> 3) & 63;
      int f    = q >> 9;            // f = jt*8 + s
      int jt = f >> 3, s = f & 7;
      int j = 32*jt + (lane & 31);
      int k = 16*s + 8*(lane >> 5) + e;
      int row = (k & ~12) | ((k & 4) << 1) | ((k & 8) >> 1); // sigma: swap bits 2,3
      float v = Wh[(layer*128 + row)*128 + j] * C2LOG2E;
      dstFH[idx] = (f16)v;
    }
    float* dstB = (float*)(base + BIAS_OFF);
    for (int idx = tid; idx < 512; idx += nth)
      dstB[idx] = ((idx < 128) ? b0[idx] : bh[idx - 128]) * C2LOG2E;
    float* dstW = (float*)(base + WO_OFF);
    for (int idx = tid; idx < 128; idx += nth) dstW[idx] = Wo[idx];
    if (tid == 0) dstW[128] = bo[0];
  }
}

// ---------------- main fused kernel ----------------
__device__ __forceinline__ f32x16 load_bias16(const float* bp){
  float4 q0 = *(const float4*)(bp +  0);
  float4 q1 = *(const float4*)(bp +  8);
  float4 q2 = *(const float4*)(bp + 16);
  float4 q3 = *(const float4*)(bp + 24);
  f32x16 a;
  a[0]=q0.x;  a[1]=q0.y;  a[2]=q0.z;  a[3]=q0.w;
  a[4]=q1.x;  a[5]=q1.y;  a[6]=q1.z;  a[7]=q1.w;
  a[8]=q2.x;  a[9]=q2.y;  a[10]=q2.z; a[11]=q2.w;
  a[12]=q3.x; a[13]=q3.y; a[14]=q3.z; a[15]=q3.w;
  return a;
}

// 256 blocks x 1024 threads (16 waves = 4/SIMD). Each wave owns ONE 32-point
// column tile and all 128 rows (acc = 4 x f32x16 = 64 regs). B-frags built in
// registers from own acc (sigma folded into packed weights). Weights LDS-
// resident: stage dp once, run 3 dp chains (zero barriers), restage ic, run ic.
__global__ __launch_bounds__(1024) void node_main(
    const float* __restrict__ tx,
    const unsigned char* __restrict__ ws,
    float* __restrict__ out)
{
  __shared__ __align__(16) unsigned char sW[FRAG0_BYTES + FRAGH_BYTES]; // 100KB
  __shared__ __align__(16) float sBias[512];
  __shared__ __align__(16) float sWo[136];

  const int tid  = threadIdx.x;
  const int wave = tid >> 6;
  const int lane = tid & 63;
  const int c    = lane & 31;
  const int hi   = lane >> 5;
  const int gp   = blockIdx.x * 512 + wave * 32 + c;

  // ---- features (hi halves redundant: broadcast loads) ----
  float4 cc = ((const float4*)tx)[gp];
  {
  }
  float x = cc.y, y = cc.z, z = cc.w;
  float xy = x*x + y*y;
  float r    = sqrtf(xy + z*z + 1e-8f);
  float rho  = sqrtf(xy + 1e-8f);
  float rin  = __builtin_amdgcn_rcpf(r);
  float rhin = __builtin_amdgcn_rcpf(rho);
  float u    = r * __builtin_amdgcn_rcpf(1.0f + r);
  float cth  = z * rin;
  float sth  = rho * rin;
  float cph  = x * rhin;
  float sph  = y * rhin;
  float th   = 0.5f * cc.x;     // a = t/2 (t0 = 0)

  auto stage = [&](const unsigned char* mb){
    for (int k = wave; k < WCHUNKS; k += 16)
      gl_lds16(mb + k*1024 + lane*16, sW + k*1024);
    for (int i = tid; i < 128; i += 1024)
      ((uint4*)sBias)[i] = ((const uint4*)(mb + BIAS_OFF))[i];
    for (int i = tid; i < 33; i += 1024)
      ((uint4*)sWo)[i] = ((const uint4*)(mb + WO_OFF))[i];
  };

  float vsum = 0.0f;

  auto run_chain = [&](int chain){
    const float gn = (chain == 0) ? -0.7745966692414834f :
                     (chain == 2) ?  0.7745966692414834f : 0.0f;
    // input B-frag: k-slot = feature index (hi half = zero padding)
    f16x8 b0f;
    #pragma unroll
    for (int e = 0; e < 8; ++e) b0f[e] = (f16)0.0f;
    if (hi == 0){
      if (chain == 3){
        b0f[0]=(f16)u;   b0f[1]=(f16)cth; b0f[2]=(f16)sth;
        b0f[3]=(f16)cph; b0f[4]=(f16)sph;
      } else {
        float ts = th * (1.0f + gn);
        b0f[0]=(f16)ts;  b0f[1]=(f16)u;   b0f[2]=(f16)cth;
        b0f[3]=(f16)sth; b0f[4]=(f16)cph; b0f[5]=(f16)sph;
      }
    }

    f32x16 acc[4];
    // ---- input layer (bias as MFMA C-in) ----
    {
      const f16x8* fr = (const f16x8*)sW;
      #pragma unroll
      for (int jt = 0; jt < 4; ++jt)
        acc[jt] = __builtin_amdgcn_mfma_f32_32x32x16_f16(
                    fr[jt*64 + lane], b0f,
                    load_bias16(&sBias[32*jt + 4*hi]), 0,0,0);
    }

    // ---- 3 hidden layers, weights resident in LDS, B in registers ----
    #pragma unroll 1
    for (int L = 0; L < 3; ++L){
      union { f16x8 v; unsigned uu[4]; } bf[8];
      #pragma unroll
      for (int jt = 0; jt < 4; ++jt)
        #pragma unroll
        for (int cq = 0; cq < 2; ++cq)
          #pragma unroll
          for (int e = 0; e < 4; ++e){
            float t0 = tanh2(acc[jt][8*cq + 2*e]);
            float t1 = tanh2(acc[jt][8*cq + 2*e + 1]);
            auto pk = __builtin_amdgcn_cvt_pkrtz(t0, t1);
            bf[2*jt + cq].uu[e] = __builtin_bit_cast(unsigned, pk);
          }
      const f16x8* fh = (const f16x8*)(sW + FRAGH_OFF + L*HLAYER_BYTES);
      #pragma unroll
      for (int jt = 0; jt < 4; ++jt){
        f32x16 t = load_bias16(&sBias[(L+1)*128 + 32*jt + 4*hi]);
        #pragma unroll
        for (int s = 0; s < 8; ++s)
          t = __builtin_amdgcn_mfma_f32_32x32x16_f16(
                fh[(jt*8 + s)*64 + lane], bf[s].v, t, 0,0,0);
        acc[jt] = t;
      }
    }

    // ---- output layer: v = sum_j tanh(h_j) * Wo[j] + bo ----
    float v = 0.0f;
    #pragma unroll
    for (int jt = 0; jt < 4; ++jt){
      const float* wp = &sWo[32*jt + 4*hi];
      float4 q0 = *(const float4*)(wp +  0);
      float4 q1 = *(const float4*)(wp +  8);
      float4 q2 = *(const float4*)(wp + 16);
      float4 q3 = *(const float4*)(wp + 24);
      f32x16 A = acc[jt];
      v += tanh2(A[0])*q0.x  + tanh2(A[1])*q0.y
         + tanh2(A[2])*q0.z  + tanh2(A[3])*q0.w
         + tanh2(A[4])*q1.x  + tanh2(A[5])*q1.y
         + tanh2(A[6])*q1.z  + tanh2(A[7])*q1.w
         + tanh2(A[8])*q2.x  + tanh2(A[9])*q2.y
         + tanh2(A[10])*q2.z + tanh2(A[11])*q2.w
         + tanh2(A[12])*q3.x + tanh2(A[13])*q3.y
         + tanh2(A[14])*q3.z + tanh2(A[15])*q3.w;
    }
    v += __shfl_xor(v, 32);            // combine the two row-halves
    v += sWo[128];                     // bo
    if (chain == 3) vsum += v;
    else {
      const float wq = (chain == 1) ? 0.8888888888888889f
                                    : 0.5555555555555556f;
      vsum = __builtin_fmaf(th * wq, v, vsum);
    }
  };

  stage(ws);                       // dp weights -> LDS
  __syncthreads();
  #pragma unroll 1
  for (int chain = 0; chain < 3; ++chain) run_chain(chain);
  __syncthreads();                 // all waves done reading dp weights
  stage(ws + MLP_BYTES);           // ic weights over same LDS
  __syncthreads();
  run_chain(3);

  if (hi == 0) out[gp] = vsum;
}

extern "C" void kernel_launch(void* const* d_in, const int* in_sizes, int n_in,
                              void* d_out, int out_size, void* d_ws, size_t ws_size,
                              hipStream_t stream)
{
  const float* tx = (const float*)d_in[0];
  pack_weights<<<64, 256, 0, stream>>>(
      (const float*)d_in[1],  (const float*)d_in[2],  (const float*)d_in[3],
      (const float*)d_in[4],  (const float*)d_in[5],  (const float*)d_in[6],
      (const float*)d_in[7],  (const float*)d_in[8],  (const float*)d_in[9],
      (const float*)d_in[10], (const float*)d_in[11], (const float*)d_in[12],
      (unsigned char*)d_ws);
  node_main<<<NPTS/512, 1024, 0, stream>>>(tx, (const unsigned char*)d_ws, (float*)d_out);
}